// Round 6
// baseline (256.802 us; speedup 1.0000x reference)
//
#include <hip/hip_runtime.h>
#include <math.h>

#define H 512
#define W 512
#define PH 256   // maxpool output dims (k3, s2, p1)
#define PW 256
#define OH 128   // unfold output dims (k5, s4, p1)
#define OW 128
#define NPLANES 96          // 32 * 3
#define TPP 16              // blocks (tiles) per plane
#define NBLOCKS (NPLANES * TPP)   // 1536; %8==0 -> bijective XCD swizzle

// d_ws layout (floats): [0,1536) partials; [1536,1632) uint counters;
// [4096, 4096+96*16384) window sums.
#define WS_PART 0
#define WS_CNT  1536
#define WS_WSUM 4096

__device__ __forceinline__ float4 fmax4(float4 a, float4 b) {
    return make_float4(fmaxf(a.x, b.x), fmaxf(a.y, b.y),
                       fmaxf(a.z, b.z), fmaxf(a.w, b.w));
}
__device__ __forceinline__ float4 fadd4(float4 a, float4 b) {
    return make_float4(a.x + b.x, a.y + b.y, a.z + b.z, a.w + b.w);
}
__device__ __forceinline__ float hsum4(float4 a) {
    return a.x + a.y + a.z + a.w;
}

// One pass over x: maxpool(3x3,s2,p1) partial sums + 5x5/s4/p1 window sums.
// The LAST block of each plane (device-scope atomic counter) computes the
// silu gate and scales the plane's window sums -> out, overlapped with the
// rest of the grid. No second full kernel, no grid sync.
__global__ __launch_bounds__(256, 4) void fused_kernel(
    const float* __restrict__ x, float* __restrict__ ws,
    float* __restrict__ out) {
    // XCD-chunked swizzle: 1536/8 = 192 consecutive logical blocks (12 whole
    // planes) per XCD -> plane halos, wsum, counter all L2-local.
    const int n = blockIdx.x;
    const int bx = (n & 7) * (NBLOCKS / 8) + (n >> 3);
    const int plane = bx / TPP;
    const int sub = bx % TPP;
    const float* __restrict__ p = x + (size_t)plane * (H * W);
    const int wid = threadIdx.x >> 6;
    const int lane = threadIdx.x & 63;
    const int t = sub * 4 + wid;          // 0..63: tile of 8 input rows
    const int col = lane << 3;

    // load 9 rows (8t-1 .. 8t+7); row -1 clamped to 0
    float4 a[9], b[9];
    #pragma unroll
    for (int j = 0; j < 9; ++j) {
        int r = 8 * t - 1 + j;
        if (r < 0) r = 0;
        const float* rp = p + r * W + col;
        a[j] = *(const float4*)(rp);
        b[j] = *(const float4*)(rp + 4);
    }

    // maxpool partial (pooled rows 4t..4t+3); clamp-dup is max-safe
    float acc = 0.f;
    #pragma unroll
    for (int k = 0; k < 4; ++k) {
        float4 va = fmax4(fmax4(a[2 * k], a[2 * k + 1]), a[2 * k + 2]);
        float4 vb = fmax4(fmax4(b[2 * k], b[2 * k + 1]), b[2 * k + 2]);
        float vL = __shfl_up(vb.w, 1, 64);
        if (lane == 0) vL = va.x;
        acc += fmaxf(fmaxf(vL, va.x), va.y);
        acc += fmaxf(fmaxf(va.y, va.z), va.w);
        acc += fmaxf(fmaxf(va.w, vb.x), vb.y);
        acc += fmaxf(fmaxf(vb.y, vb.z), vb.w);
    }
    #pragma unroll
    for (int off = 32; off > 0; off >>= 1)
        acc += __shfl_down(acc, off, 64);
    __shared__ float smem[4];
    if (lane == 0) smem[wid] = acc;

    // 5x5 window sums, out rows 2t (a[0..4]) and 2t+1 (a[4..8]);
    // j=0 is the zero-pad row when t==0
    float4 z = make_float4(0.f, 0.f, 0.f, 0.f);
    float4 a0 = (t == 0) ? z : a[0];
    float4 b0 = (t == 0) ? z : b[0];
    float4 sa0 = fadd4(fadd4(fadd4(a0, a[1]), fadd4(a[2], a[3])), a[4]);
    float4 sb0 = fadd4(fadd4(fadd4(b0, b[1]), fadd4(b[2], b[3])), b[4]);
    float4 sa1 = fadd4(fadd4(fadd4(a[4], a[5]), fadd4(a[6], a[7])), a[8]);
    float4 sb1 = fadd4(fadd4(fadd4(b[4], b[5]), fadd4(b[6], b[7])), b[8]);

    float* wrow = ws + WS_WSUM + (size_t)plane * (OH * OW);
    {
        float sL = __shfl_up(sb0.w, 1, 64);
        if (lane == 0) sL = 0.f;          // zero pad col -1
        *(float2*)&wrow[(2 * t) * OW + 2 * lane] =
            make_float2(sL + hsum4(sa0), sa0.w + hsum4(sb0));
    }
    {
        float sL = __shfl_up(sb1.w, 1, 64);
        if (lane == 0) sL = 0.f;
        *(float2*)&wrow[(2 * t + 1) * OW + 2 * lane] =
            make_float2(sL + hsum4(sa1), sa1.w + hsum4(sb1));
    }

    __syncthreads();
    if (threadIdx.x == 0)
        ws[WS_PART + plane * TPP + sub] =
            smem[0] + smem[1] + smem[2] + smem[3];

    // publish this block's wsum rows + partial (device scope), then count
    __threadfence();
    __shared__ int is_last;
    if (threadIdx.x == 0) {
        unsigned* cnt = (unsigned*)(ws + WS_CNT);
        unsigned old = atomicAdd(&cnt[plane], 1u);
        is_last = (old == TPP - 1);
    }
    __syncthreads();
    if (!is_last) return;

    // last block of this plane: acquire, compute gate, scale -> out
    __threadfence();
    float s = 0.f;
    #pragma unroll
    for (int i = 0; i < TPP; ++i)
        s += ws[WS_PART + plane * TPP + i];
    s *= (1.0f / (float)(PH * PW));
    const float gate = s / (1.0f + expf(-s));
    const float scale = gate * (1.0f / 25.0f);

    const float4* src = (const float4*)(ws + WS_WSUM + (size_t)plane * (OH * OW));
    float4* dst = (float4*)(out + (size_t)plane * (OH * OW));
    #pragma unroll
    for (int i = 0; i < 16; ++i) {        // 4096 float4 / 256 threads
        const int idx = i * 256 + threadIdx.x;
        float4 v = src[idx];
        dst[idx] = make_float4(v.x * scale, v.y * scale,
                               v.z * scale, v.w * scale);
    }
}

extern "C" void kernel_launch(void* const* d_in, const int* in_sizes, int n_in,
                              void* d_out, int out_size, void* d_ws, size_t ws_size,
                              hipStream_t stream) {
    const float* x = (const float*)d_in[0];
    float* out = (float*)d_out;
    float* ws = (float*)d_ws;

    // zero the per-plane arrival counters (harness does NOT re-poison ws
    // between replays; counters must start at 0 every call)
    hipMemsetAsync((char*)d_ws + WS_CNT * sizeof(float), 0,
                   NPLANES * sizeof(unsigned), stream);
    fused_kernel<<<NBLOCKS, 256, 0, stream>>>(x, ws, out);
}

// Round 7
// 28.126 us; speedup vs baseline: 9.1304x; 9.1304x over previous
//
#include <hip/hip_runtime.h>
#include <math.h>

#define H 512
#define W 512
#define PH 256   // maxpool output dims (k3, s2, p1)
#define PW 256
#define OH 128   // unfold output dims (k5, s4, p1)
#define OW 128
#define NPLANES 96          // 32 * 3
#define TPP 16              // blocks per plane
#define NBLOCKS (NPLANES * TPP)   // 1536; %8==0 -> bijective XCD swizzle

// d_ws layout (floats): [0,1536) partials; [2048, 2048+96*16384) window sums
#define WS_PART 0
#define WS_WSUM 2048

__device__ __forceinline__ float4 fmax4(float4 a, float4 b) {
    return make_float4(fmaxf(a.x, b.x), fmaxf(a.y, b.y),
                       fmaxf(a.z, b.z), fmaxf(a.w, b.w));
}
__device__ __forceinline__ float4 fadd4(float4 a, float4 b) {
    return make_float4(a.x + b.x, a.y + b.y, a.z + b.z, a.w + b.w);
}
__device__ __forceinline__ float hsum4(float4 a) {
    return a.x + a.y + a.z + a.w;
}

// pooled-row horizontal max: rows (a0,b0),(a1,b1),(a2,b2) -> 4 pooled cols/lane
__device__ __forceinline__ void hmax_acc(
    float4 a0, float4 b0, float4 a1, float4 b1, float4 a2, float4 b2,
    int lane, float& acc) {
    float4 va = fmax4(fmax4(a0, a1), a2);
    float4 vb = fmax4(fmax4(b0, b1), b2);
    float vL = __shfl_up(vb.w, 1, 64);
    if (lane == 0) vL = va.x;          // duplicate: max-safe
    acc += fmaxf(fmaxf(vL, va.x), va.y);
    acc += fmaxf(fmaxf(va.y, va.z), va.w);
    acc += fmaxf(fmaxf(va.w, vb.x), vb.y);
    acc += fmaxf(fmaxf(vb.y, vb.z), vb.w);
}

// emit one unfold output row (128 cols, 2 per lane) from 5-row col sums
__device__ __forceinline__ void emit_row(
    float4 SA, float4 SB, int lane, float* __restrict__ wrow) {
    float sL = __shfl_up(SB.w, 1, 64);
    if (lane == 0) sL = 0.f;           // zero pad at col -1
    *(float2*)&wrow[2 * lane] =
        make_float2(sL + hsum4(SA), SA.w + hsum4(SB));
}

// Fused pass, register-lean (target <=64 VGPR -> 8 waves/SIMD):
// wave t owns input rows 8t-1..8t+7, processed in two 5-row phases
// (peak live = 10 float4). Produces maxpool(3x3,s2,p1) partial sums and
// 5x5/s4/p1 window sums (rows 2t, 2t+1).
__global__ __launch_bounds__(256, 8) void fused_kernel(
    const float* __restrict__ x, float* __restrict__ ws) {
    const int n = blockIdx.x;
    const int bx = (n & 7) * (NBLOCKS / 8) + (n >> 3);   // XCD-chunked swizzle
    const int plane = bx / TPP;
    const int sub = bx % TPP;
    const int wid = threadIdx.x >> 6;
    const int lane = threadIdx.x & 63;
    const int t = sub * 4 + wid;          // 0..63
    const float* __restrict__ base = x + (size_t)plane * (H * W) + (lane << 3);
    float* __restrict__ wrow = ws + WS_WSUM + (size_t)plane * (OH * OW);

#define LDROW(va, vb, r)                                            \
    {                                                               \
        const float* q = base + (size_t)(r) * W;                    \
        va = *(const float4*)(q);                                   \
        vb = *(const float4*)(q + 4);                               \
    }

    float4 A0, B0, A1, B1, A2, B2, A3, B3, A4, B4;
    float acc = 0.f;

    // ---- phase A: rows 8t-1 .. 8t+3 ----
    {
        int r0 = 8 * t - 1;
        if (r0 < 0) r0 = 0;               // clamp-dup, max-safe
        LDROW(A0, B0, r0);
    }
    LDROW(A1, B1, 8 * t);
    LDROW(A2, B2, 8 * t + 1);
    LDROW(A3, B3, 8 * t + 2);
    LDROW(A4, B4, 8 * t + 3);

    hmax_acc(A0, B0, A1, B1, A2, B2, lane, acc);   // pooled row 4t
    hmax_acc(A2, B2, A3, B3, A4, B4, lane, acc);   // pooled row 4t+1

    if (t == 0) {                          // row -1 is zero pad for the SUM
        A0 = make_float4(0.f, 0.f, 0.f, 0.f);
        B0 = make_float4(0.f, 0.f, 0.f, 0.f);
    }
    {
        float4 SA = fadd4(fadd4(fadd4(A0, A1), fadd4(A2, A3)), A4);
        float4 SB = fadd4(fadd4(fadd4(B0, B1), fadd4(B2, B3)), B4);
        emit_row(SA, SB, lane, wrow + (size_t)(2 * t) * OW);
    }

    // ---- phase B: rows 8t+3 .. 8t+7 (A4/B4 = row 8t+3 kept live) ----
    LDROW(A0, B0, 8 * t + 4);
    LDROW(A1, B1, 8 * t + 5);
    LDROW(A2, B2, 8 * t + 6);
    LDROW(A3, B3, 8 * t + 7);

    hmax_acc(A4, B4, A0, B0, A1, B1, lane, acc);   // pooled row 4t+2
    hmax_acc(A1, B1, A2, B2, A3, B3, lane, acc);   // pooled row 4t+3

    {
        float4 SA = fadd4(fadd4(fadd4(A4, A0), fadd4(A1, A2)), A3);
        float4 SB = fadd4(fadd4(fadd4(B4, B0), fadd4(B1, B2)), B3);
        emit_row(SA, SB, lane, wrow + (size_t)(2 * t + 1) * OW);
    }
#undef LDROW

    // block-reduce maxpool partial -> ws[plane*TPP + sub]
    #pragma unroll
    for (int off = 32; off > 0; off >>= 1)
        acc += __shfl_down(acc, off, 64);
    __shared__ float smem[4];
    if (lane == 0) smem[wid] = acc;
    __syncthreads();
    if (threadIdx.x == 0)
        ws[WS_PART + plane * TPP + sub] =
            smem[0] + smem[1] + smem[2] + smem[3];
}

// Scale pass: out = wsum * silu(mean_pooled) / 25.  96 planes * 4 blocks.
__global__ __launch_bounds__(256) void scale_kernel(
    const float* __restrict__ ws, float* __restrict__ out) {
    const int bx = blockIdx.x;
    const int plane = bx >> 2;
    const int quarter = bx & 3;

    float s = 0.f;
    #pragma unroll
    for (int i = 0; i < TPP; ++i)
        s += ws[WS_PART + plane * TPP + i];
    s *= (1.0f / (float)(PH * PW));
    const float gate = s / (1.0f + expf(-s));
    const float scale = gate * (1.0f / 25.0f);

    const float4* src = (const float4*)(ws + WS_WSUM + (size_t)plane * (OH * OW));
    float4* dst = (float4*)(out + (size_t)plane * (OH * OW));
    const int base = quarter * 1024 + threadIdx.x;   // float4 index
    #pragma unroll
    for (int i = 0; i < 4; ++i) {
        const int idx = base + i * 256;
        float4 v = src[idx];
        dst[idx] = make_float4(v.x * scale, v.y * scale,
                               v.z * scale, v.w * scale);
    }
}

extern "C" void kernel_launch(void* const* d_in, const int* in_sizes, int n_in,
                              void* d_out, int out_size, void* d_ws, size_t ws_size,
                              hipStream_t stream) {
    const float* x = (const float*)d_in[0];
    float* out = (float*)d_out;
    float* ws = (float*)d_ws;

    fused_kernel<<<NBLOCKS, 256, 0, stream>>>(x, ws);
    scale_kernel<<<NPLANES * 4, 256, 0, stream>>>(ws, out);
}

// Round 9
// 26.336 us; speedup vs baseline: 9.7508x; 1.0680x over previous
//
#include <hip/hip_runtime.h>
#include <math.h>

#define H 512
#define W 512
#define PH 256   // maxpool output dims (k3, s2, p1)
#define PW 256
#define OH 128   // unfold output dims (k5, s4, p1)
#define OW 128
#define NPLANES 96          // 32 * 3
#define TPP 16              // blocks per plane in fused pass
#define WS_PART 0
#define WS_WSUM 2048

typedef float vf4 __attribute__((ext_vector_type(4)));   // native vec for builtins

__device__ __forceinline__ float4 fmax4(float4 a, float4 b) {
    return make_float4(fmaxf(a.x, b.x), fmaxf(a.y, b.y),
                       fmaxf(a.z, b.z), fmaxf(a.w, b.w));
}
__device__ __forceinline__ float4 fadd4(float4 a, float4 b) {
    return make_float4(a.x + b.x, a.y + b.y, a.z + b.z, a.w + b.w);
}
__device__ __forceinline__ float hsum4(float4 a) {
    return a.x + a.y + a.z + a.w;
}

// Fused pass (R3-proven body, max MLP: all 18 loads independent/in-flight):
// wave t owns input rows 8t-1..8t+7; produces maxpool(3x3,s2,p1) partial
// sums -> ws and 5x5/s4/p1 window sums (out rows 2t, 2t+1) -> ws.
__global__ __launch_bounds__(256, 4) void fused_kernel(
    const float* __restrict__ x, float* __restrict__ ws) {
    const int bx = blockIdx.x;
    const int plane = bx / TPP;
    const int sub = bx % TPP;
    const float* __restrict__ p = x + (size_t)plane * (H * W);
    const int wid = threadIdx.x >> 6;
    const int lane = threadIdx.x & 63;
    const int t = sub * 4 + wid;          // 0..63: tile of 8 input rows
    const int col = lane << 3;

    // load 9 rows (8t-1 .. 8t+7); row -1 clamped to 0
    float4 a[9], b[9];
    #pragma unroll
    for (int j = 0; j < 9; ++j) {
        int r = 8 * t - 1 + j;
        if (r < 0) r = 0;
        const float* rp = p + r * W + col;
        a[j] = *(const float4*)(rp);
        b[j] = *(const float4*)(rp + 4);
    }

    // maxpool partial (pooled rows 4t..4t+3); clamp-dup is max-safe
    float acc = 0.f;
    #pragma unroll
    for (int k = 0; k < 4; ++k) {
        float4 va = fmax4(fmax4(a[2 * k], a[2 * k + 1]), a[2 * k + 2]);
        float4 vb = fmax4(fmax4(b[2 * k], b[2 * k + 1]), b[2 * k + 2]);
        float vL = __shfl_up(vb.w, 1, 64);
        if (lane == 0) vL = va.x;
        acc += fmaxf(fmaxf(vL, va.x), va.y);
        acc += fmaxf(fmaxf(va.y, va.z), va.w);
        acc += fmaxf(fmaxf(va.w, vb.x), vb.y);
        acc += fmaxf(fmaxf(vb.y, vb.z), vb.w);
    }
    #pragma unroll
    for (int off = 32; off > 0; off >>= 1)
        acc += __shfl_down(acc, off, 64);
    __shared__ float smem[4];
    if (lane == 0) smem[wid] = acc;

    // 5x5 window sums, out rows 2t (a[0..4]) and 2t+1 (a[4..8]);
    // j=0 is the zero-pad row when t==0
    float4 z = make_float4(0.f, 0.f, 0.f, 0.f);
    float4 a0 = (t == 0) ? z : a[0];
    float4 b0 = (t == 0) ? z : b[0];
    float4 sa0 = fadd4(fadd4(fadd4(a0, a[1]), fadd4(a[2], a[3])), a[4]);
    float4 sb0 = fadd4(fadd4(fadd4(b0, b[1]), fadd4(b[2], b[3])), b[4]);
    float4 sa1 = fadd4(fadd4(fadd4(a[4], a[5]), fadd4(a[6], a[7])), a[8]);
    float4 sb1 = fadd4(fadd4(fadd4(b[4], b[5]), fadd4(b[6], b[7])), b[8]);

    float* wrow = ws + WS_WSUM + (size_t)plane * (OH * OW);
    {
        float sL = __shfl_up(sb0.w, 1, 64);
        if (lane == 0) sL = 0.f;          // zero pad col -1
        *(float2*)&wrow[(2 * t) * OW + 2 * lane] =
            make_float2(sL + hsum4(sa0), sa0.w + hsum4(sb0));
    }
    {
        float sL = __shfl_up(sb1.w, 1, 64);
        if (lane == 0) sL = 0.f;
        *(float2*)&wrow[(2 * t + 1) * OW + 2 * lane] =
            make_float2(sL + hsum4(sa1), sa1.w + hsum4(sb1));
    }

    __syncthreads();
    if (threadIdx.x == 0)
        ws[WS_PART + plane * TPP + sub] =
            smem[0] + smem[1] + smem[2] + smem[3];
}

// Scale pass: out = wsum * silu(mean_pooled) / 25.
// Max parallelism: 1536 blocks x 256 threads = exactly one float4 per
// thread (zero loop-carried work, tail-latency minimal). out is never
// re-read -> nontemporal store.
__global__ __launch_bounds__(256) void scale_kernel(
    const float* __restrict__ ws, float* __restrict__ out) {
    const int bx = blockIdx.x;
    const int plane = bx >> 4;            // 16 blocks per plane
    const int sub = bx & 15;

    float s = 0.f;
    #pragma unroll
    for (int i = 0; i < TPP; ++i)
        s += ws[WS_PART + plane * TPP + i];
    s *= (1.0f / (float)(PH * PW));
    const float gate = s / (1.0f + expf(-s));
    const float scale = gate * (1.0f / 25.0f);

    const vf4* src = (const vf4*)(ws + WS_WSUM + (size_t)plane * (OH * OW));
    vf4* dst = (vf4*)(out + (size_t)plane * (OH * OW));
    const int idx = sub * 256 + threadIdx.x;      // 0..4095 within plane
    vf4 v = src[idx];
    v *= scale;
    __builtin_nontemporal_store(v, &dst[idx]);
}

extern "C" void kernel_launch(void* const* d_in, const int* in_sizes, int n_in,
                              void* d_out, int out_size, void* d_ws, size_t ws_size,
                              hipStream_t stream) {
    const float* x = (const float*)d_in[0];
    float* out = (float*)d_out;
    float* ws = (float*)d_ws;

    fused_kernel<<<NPLANES * TPP, 256, 0, stream>>>(x, ws);
    scale_kernel<<<NPLANES * 16, 256, 0, stream>>>(ws, out);
}

// Round 10
// 25.063 us; speedup vs baseline: 10.2462x; 1.0508x over previous
//
#include <hip/hip_runtime.h>
#include <math.h>

#define H 512
#define W 512
#define PH 256   // maxpool output dims (k3, s2, p1)
#define PW 256
#define OH 128   // unfold output dims (k5, s4, p1)
#define OW 128
#define NPLANES 96          // 32 * 3
#define TPP 16              // blocks per plane in fused pass
#define WS_PART 0           // float offset: 1536 partials
#define WSUM_BYTE_OFF 8192  // byte offset of bf16 wsum region (96*16384*2 B)

typedef float vf4 __attribute__((ext_vector_type(4)));   // native vec for builtins

__device__ __forceinline__ float4 fmax4(float4 a, float4 b) {
    return make_float4(fmaxf(a.x, b.x), fmaxf(a.y, b.y),
                       fmaxf(a.z, b.z), fmaxf(a.w, b.w));
}
__device__ __forceinline__ float4 fadd4(float4 a, float4 b) {
    return make_float4(a.x + b.x, a.y + b.y, a.z + b.z, a.w + b.w);
}
__device__ __forceinline__ float hsum4(float4 a) {
    return a.x + a.y + a.z + a.w;
}
// f32 -> bf16 bits, round-to-nearest-even (inputs are finite)
__device__ __forceinline__ unsigned f2bf(float f) {
    unsigned u = __float_as_uint(f);
    u += 0x7fffu + ((u >> 16) & 1u);
    return u >> 16;
}

// Fused pass (R3-proven body, max MLP: all 18 loads independent/in-flight):
// wave t owns input rows 8t-1..8t+7; produces maxpool(3x3,s2,p1) partial
// sums -> ws and 5x5/s4/p1 window sums (out rows 2t, 2t+1) as bf16 -> ws.
__global__ __launch_bounds__(256, 4) void fused_kernel(
    const float* __restrict__ x, float* __restrict__ ws) {
    const int bx = blockIdx.x;
    const int plane = bx / TPP;
    const int sub = bx % TPP;
    const float* __restrict__ p = x + (size_t)plane * (H * W);
    const int wid = threadIdx.x >> 6;
    const int lane = threadIdx.x & 63;
    const int t = sub * 4 + wid;          // 0..63: tile of 8 input rows
    const int col = lane << 3;

    // load 9 rows (8t-1 .. 8t+7); row -1 clamped to 0
    float4 a[9], b[9];
    #pragma unroll
    for (int j = 0; j < 9; ++j) {
        int r = 8 * t - 1 + j;
        if (r < 0) r = 0;
        const float* rp = p + r * W + col;
        a[j] = *(const float4*)(rp);
        b[j] = *(const float4*)(rp + 4);
    }

    // maxpool partial (pooled rows 4t..4t+3); clamp-dup is max-safe
    float acc = 0.f;
    #pragma unroll
    for (int k = 0; k < 4; ++k) {
        float4 va = fmax4(fmax4(a[2 * k], a[2 * k + 1]), a[2 * k + 2]);
        float4 vb = fmax4(fmax4(b[2 * k], b[2 * k + 1]), b[2 * k + 2]);
        float vL = __shfl_up(vb.w, 1, 64);
        if (lane == 0) vL = va.x;
        acc += fmaxf(fmaxf(vL, va.x), va.y);
        acc += fmaxf(fmaxf(va.y, va.z), va.w);
        acc += fmaxf(fmaxf(va.w, vb.x), vb.y);
        acc += fmaxf(fmaxf(vb.y, vb.z), vb.w);
    }
    #pragma unroll
    for (int off = 32; off > 0; off >>= 1)
        acc += __shfl_down(acc, off, 64);
    __shared__ float smem[4];
    if (lane == 0) smem[wid] = acc;

    // 5x5 window sums, out rows 2t (a[0..4]) and 2t+1 (a[4..8]);
    // j=0 is the zero-pad row when t==0
    float4 z = make_float4(0.f, 0.f, 0.f, 0.f);
    float4 a0 = (t == 0) ? z : a[0];
    float4 b0 = (t == 0) ? z : b[0];
    float4 sa0 = fadd4(fadd4(fadd4(a0, a[1]), fadd4(a[2], a[3])), a[4]);
    float4 sb0 = fadd4(fadd4(fadd4(b0, b[1]), fadd4(b[2], b[3])), b[4]);
    float4 sa1 = fadd4(fadd4(fadd4(a[4], a[5]), fadd4(a[6], a[7])), a[8]);
    float4 sb1 = fadd4(fadd4(fadd4(b[4], b[5]), fadd4(b[6], b[7])), b[8]);

    unsigned* wrow =
        (unsigned*)((char*)ws + WSUM_BYTE_OFF) + (size_t)plane * (OH * OW / 2);
    {
        float sL = __shfl_up(sb0.w, 1, 64);
        if (lane == 0) sL = 0.f;          // zero pad col -1
        float o0 = sL + hsum4(sa0);       // ow = 2l
        float o1 = sa0.w + hsum4(sb0);    // ow = 2l+1
        wrow[(2 * t) * (OW / 2) + lane] = f2bf(o0) | (f2bf(o1) << 16);
    }
    {
        float sL = __shfl_up(sb1.w, 1, 64);
        if (lane == 0) sL = 0.f;
        float o0 = sL + hsum4(sa1);
        float o1 = sa1.w + hsum4(sb1);
        wrow[(2 * t + 1) * (OW / 2) + lane] = f2bf(o0) | (f2bf(o1) << 16);
    }

    __syncthreads();
    if (threadIdx.x == 0)
        ws[WS_PART + plane * TPP + sub] =
            smem[0] + smem[1] + smem[2] + smem[3];
}

// Scale pass: out = wsum * silu(mean_pooled) / 25.
// 1536 blocks x 256 threads: one uint2 (4 bf16) load -> one float4 nt-store
// per thread. Same bx->data mapping as fused_kernel -> same XCD -> L2 hits.
__global__ __launch_bounds__(256) void scale_kernel(
    const float* __restrict__ ws, float* __restrict__ out) {
    const int bx = blockIdx.x;
    const int plane = bx >> 4;            // 16 blocks per plane
    const int sub = bx & 15;

    float s = 0.f;
    #pragma unroll
    for (int i = 0; i < TPP; ++i)
        s += ws[WS_PART + plane * TPP + i];
    s *= (1.0f / (float)(PH * PW));
    const float gate = s / (1.0f + expf(-s));
    const float scale = gate * (1.0f / 25.0f);

    const uint2* src =
        (const uint2*)((const char*)ws + WSUM_BYTE_OFF) +
        (size_t)plane * (OH * OW / 4);
    vf4* dst = (vf4*)(out + (size_t)plane * (OH * OW));
    const int idx = sub * 256 + threadIdx.x;      // 0..4095 within plane
    uint2 u = src[idx];
    vf4 v;
    v.x = __uint_as_float(u.x << 16);
    v.y = __uint_as_float(u.x & 0xffff0000u);
    v.z = __uint_as_float(u.y << 16);
    v.w = __uint_as_float(u.y & 0xffff0000u);
    v *= scale;
    __builtin_nontemporal_store(v, &dst[idx]);
}

extern "C" void kernel_launch(void* const* d_in, const int* in_sizes, int n_in,
                              void* d_out, int out_size, void* d_ws, size_t ws_size,
                              hipStream_t stream) {
    const float* x = (const float*)d_in[0];
    float* out = (float*)d_out;
    float* ws = (float*)d_ws;

    fused_kernel<<<NPLANES * TPP, 256, 0, stream>>>(x, ws);
    scale_kernel<<<NPLANES * TPP, 256, 0, stream>>>(ws, out);
}

// Round 11
// 24.891 us; speedup vs baseline: 10.3171x; 1.0069x over previous
//
#include <hip/hip_runtime.h>
#include <math.h>

#define H 512
#define W 512
#define PH 256   // maxpool output dims (k3, s2, p1)
#define PW 256
#define OH 128   // unfold output dims (k5, s4, p1)
#define OW 128
#define NPLANES 96          // 32 * 3
#define TPP 16              // blocks per plane in fused pass
#define NBLOCKS (NPLANES * TPP)   // 1536; %8==0 -> bijective XCD swizzle
#define WS_PART 0           // float offset: 1536 partials
#define WSUM_BYTE_OFF 8192  // byte offset of bf16 wsum region (96*16384*2 B)

typedef float vf4 __attribute__((ext_vector_type(4)));   // native vec for builtins

__device__ __forceinline__ float4 fmax4(float4 a, float4 b) {
    return make_float4(fmaxf(a.x, b.x), fmaxf(a.y, b.y),
                       fmaxf(a.z, b.z), fmaxf(a.w, b.w));
}
__device__ __forceinline__ float4 fadd4(float4 a, float4 b) {
    return make_float4(a.x + b.x, a.y + b.y, a.z + b.z, a.w + b.w);
}
__device__ __forceinline__ float hsum4(float4 a) {
    return a.x + a.y + a.z + a.w;
}
// f32 -> bf16 bits, round-to-nearest-even (inputs are finite)
__device__ __forceinline__ unsigned f2bf(float f) {
    unsigned u = __float_as_uint(f);
    u += 0x7fffu + ((u >> 16) & 1u);
    return u >> 16;
}

// XCD-chunked swizzle: hw block n -> logical block. 1536/8 = 192 consecutive
// logical blocks (12 whole planes) per XCD -> halo rows, partials and wsum
// all stay in one XCD's L2 (per-XCD L2s are not cross-coherent/shared).
__device__ __forceinline__ int xcd_swizzle(int n) {
    return (n & 7) * (NBLOCKS / 8) + (n >> 3);
}

// Fused pass (R3-proven body, max MLP: all 18 loads independent/in-flight):
// wave t owns input rows 8t-1..8t+7; produces maxpool(3x3,s2,p1) partial
// sums -> ws and 5x5/s4/p1 window sums (out rows 2t, 2t+1) as bf16 -> ws.
__global__ __launch_bounds__(256, 4) void fused_kernel(
    const float* __restrict__ x, float* __restrict__ ws) {
    const int bx = xcd_swizzle(blockIdx.x);
    const int plane = bx / TPP;
    const int sub = bx % TPP;
    const float* __restrict__ p = x + (size_t)plane * (H * W);
    const int wid = threadIdx.x >> 6;
    const int lane = threadIdx.x & 63;
    const int t = sub * 4 + wid;          // 0..63: tile of 8 input rows
    const int col = lane << 3;

    // load 9 rows (8t-1 .. 8t+7); row -1 clamped to 0
    float4 a[9], b[9];
    #pragma unroll
    for (int j = 0; j < 9; ++j) {
        int r = 8 * t - 1 + j;
        if (r < 0) r = 0;
        const float* rp = p + r * W + col;
        a[j] = *(const float4*)(rp);
        b[j] = *(const float4*)(rp + 4);
    }

    // maxpool partial (pooled rows 4t..4t+3); clamp-dup is max-safe
    float acc = 0.f;
    #pragma unroll
    for (int k = 0; k < 4; ++k) {
        float4 va = fmax4(fmax4(a[2 * k], a[2 * k + 1]), a[2 * k + 2]);
        float4 vb = fmax4(fmax4(b[2 * k], b[2 * k + 1]), b[2 * k + 2]);
        float vL = __shfl_up(vb.w, 1, 64);
        if (lane == 0) vL = va.x;
        acc += fmaxf(fmaxf(vL, va.x), va.y);
        acc += fmaxf(fmaxf(va.y, va.z), va.w);
        acc += fmaxf(fmaxf(va.w, vb.x), vb.y);
        acc += fmaxf(fmaxf(vb.y, vb.z), vb.w);
    }
    #pragma unroll
    for (int off = 32; off > 0; off >>= 1)
        acc += __shfl_down(acc, off, 64);
    __shared__ float smem[4];
    if (lane == 0) smem[wid] = acc;

    // 5x5 window sums, out rows 2t (a[0..4]) and 2t+1 (a[4..8]);
    // j=0 is the zero-pad row when t==0
    float4 z = make_float4(0.f, 0.f, 0.f, 0.f);
    float4 a0 = (t == 0) ? z : a[0];
    float4 b0 = (t == 0) ? z : b[0];
    float4 sa0 = fadd4(fadd4(fadd4(a0, a[1]), fadd4(a[2], a[3])), a[4]);
    float4 sb0 = fadd4(fadd4(fadd4(b0, b[1]), fadd4(b[2], b[3])), b[4]);
    float4 sa1 = fadd4(fadd4(fadd4(a[4], a[5]), fadd4(a[6], a[7])), a[8]);
    float4 sb1 = fadd4(fadd4(fadd4(b[4], b[5]), fadd4(b[6], b[7])), b[8]);

    unsigned* wrow =
        (unsigned*)((char*)ws + WSUM_BYTE_OFF) + (size_t)plane * (OH * OW / 2);
    {
        float sL = __shfl_up(sb0.w, 1, 64);
        if (lane == 0) sL = 0.f;          // zero pad col -1
        float o0 = sL + hsum4(sa0);       // ow = 2l
        float o1 = sa0.w + hsum4(sb0);    // ow = 2l+1
        wrow[(2 * t) * (OW / 2) + lane] = f2bf(o0) | (f2bf(o1) << 16);
    }
    {
        float sL = __shfl_up(sb1.w, 1, 64);
        if (lane == 0) sL = 0.f;
        float o0 = sL + hsum4(sa1);
        float o1 = sa1.w + hsum4(sb1);
        wrow[(2 * t + 1) * (OW / 2) + lane] = f2bf(o0) | (f2bf(o1) << 16);
    }

    __syncthreads();
    if (threadIdx.x == 0)
        ws[WS_PART + plane * TPP + sub] =
            smem[0] + smem[1] + smem[2] + smem[3];
}

// Scale pass: out = wsum * silu(mean_pooled) / 25.
// Same swizzle -> plane's scale blocks run on the XCD whose L2 holds its
// wsum. One uint2 (4 bf16) load -> one float4 nt-store per thread.
__global__ __launch_bounds__(256) void scale_kernel(
    const float* __restrict__ ws, float* __restrict__ out) {
    const int bx = xcd_swizzle(blockIdx.x);
    const int plane = bx >> 4;            // 16 blocks per plane
    const int sub = bx & 15;

    float s = 0.f;
    #pragma unroll
    for (int i = 0; i < TPP; ++i)
        s += ws[WS_PART + plane * TPP + i];
    s *= (1.0f / (float)(PH * PW));
    const float gate = s / (1.0f + expf(-s));
    const float scale = gate * (1.0f / 25.0f);

    const uint2* src =
        (const uint2*)((const char*)ws + WSUM_BYTE_OFF) +
        (size_t)plane * (OH * OW / 4);
    vf4* dst = (vf4*)(out + (size_t)plane * (OH * OW));
    const int idx = sub * 256 + threadIdx.x;      // 0..4095 within plane
    uint2 u = src[idx];
    vf4 v;
    v.x = __uint_as_float(u.x << 16);
    v.y = __uint_as_float(u.x & 0xffff0000u);
    v.z = __uint_as_float(u.y << 16);
    v.w = __uint_as_float(u.y & 0xffff0000u);
    v *= scale;
    __builtin_nontemporal_store(v, &dst[idx]);
}

extern "C" void kernel_launch(void* const* d_in, const int* in_sizes, int n_in,
                              void* d_out, int out_size, void* d_ws, size_t ws_size,
                              hipStream_t stream) {
    const float* x = (const float*)d_in[0];
    float* out = (float*)d_out;
    float* ws = (float*)d_ws;

    fused_kernel<<<NBLOCKS, 256, 0, stream>>>(x, ws);
    scale_kernel<<<NBLOCKS, 256, 0, stream>>>(ws, out);
}